// Round 1
// baseline (4025.958 us; speedup 1.0000x reference)
//
#include <hip/hip_runtime.h>
#include <hip/hip_bf16.h>

// Bi-LSTM persistent kernel. B=32, T=512, D=H=512.
// 256 WGs (128 per direction), custom per-direction global barrier per timestep.
#define Bz 32
#define Tz 512
#define Dz 512
#define Hz 512
#define GPD 128   // workgroups per direction
#define JPW 4     // h-columns owned per WG (=> 16 gate columns = one MFMA N tile)

typedef __attribute__((ext_vector_type(8))) short short8;
typedef __attribute__((ext_vector_type(4))) short short4v;
typedef __attribute__((ext_vector_type(4))) float f32x4;

// workspace layout (bytes)
#define WS_CNT 0                       // 2 counters, 128B apart
#define WS_H   256                     // h buffers: dir(2) x parity(2) x 32x512 bf16 = 4*32768
#define WS_X   (256 + 4*32768)         // x in bf16: 32*512*512*2 = 16 MB
#define WS_NEED ((size_t)WS_X + (size_t)Bz*Tz*Dz*2)

__device__ __forceinline__ unsigned short f2bf(float f) {
    return __builtin_bit_cast(unsigned short, __float2bfloat16(f));
}
__device__ __forceinline__ float rcp_(float x) { return __builtin_amdgcn_rcpf(x); }
__device__ __forceinline__ float fsig(float x) { return rcp_(1.0f + __expf(-x)); }
__device__ __forceinline__ float ftanh(float x) {
    float t = __expf(-2.0f * fabsf(x));
    return copysignf((1.0f - t) * rcp_(1.0f + t), x);
}
__device__ __forceinline__ short8 mk8(unsigned long long lo, unsigned long long hi) {
    short4v a = __builtin_bit_cast(short4v, lo);
    short4v b = __builtin_bit_cast(short4v, hi);
    short8 r;
    r[0]=a[0]; r[1]=a[1]; r[2]=a[2]; r[3]=a[3];
    r[4]=b[0]; r[5]=b[1]; r[6]=b[2]; r[7]=b[3];
    return r;
}

// Zero counters + h buffers; convert x fp32 -> bf16 into ws (if it fits).
__global__ void init_kernel(const float* __restrict__ x, unsigned char* __restrict__ ws, int do_x) {
    int tid = blockIdx.x * blockDim.x + threadIdx.x;
    unsigned int* w32 = (unsigned int*)ws;
    if (tid < (WS_X / 4)) w32[tid] = 0u;   // counters + all h buffers = 131328 B
    if (do_x) {
        const int n4 = (Bz * Tz * Dz) / 4;
        if (tid < n4) {
            const float4* xin = (const float4*)x;
            float4 v = xin[tid];
            unsigned int u0 = (unsigned)f2bf(v.x) | ((unsigned)f2bf(v.y) << 16);
            unsigned int u1 = (unsigned)f2bf(v.z) | ((unsigned)f2bf(v.w) << 16);
            unsigned int* xo = (unsigned int*)(ws + WS_X);
            xo[tid * 2]     = u0;
            xo[tid * 2 + 1] = u1;
        }
    }
}

template <bool XB>
__launch_bounds__(256)
__global__ void lstm_kernel(const float* __restrict__ xf,
                            const float* __restrict__ Wf, const float* __restrict__ bf,
                            const float* __restrict__ Wb, const float* __restrict__ bb,
                            float* __restrict__ out, unsigned char* __restrict__ ws) {
    const int dir  = blockIdx.x & 1;
    const int wg   = blockIdx.x >> 1;
    const int j0   = wg * JPW;
    const int tid  = threadIdx.x;
    const int wave = tid >> 6;
    const int lane = tid & 63;
    const int nidx = lane & 15;   // B-frag col n / A-frag row m
    const int quad = lane >> 4;

    const float* W    = dir ? Wb : Wf;
    const float* bias = dir ? bb : bf;

    unsigned int* cnt = (unsigned int*)(ws + WS_CNT + dir * 128);
    unsigned char* hbase = ws + WS_H + dir * 2 * 32768;   // + parity*32768
    const unsigned short* xbf = (const unsigned short*)(ws + WS_X);

    __shared__ float part[4][2][16][17];   // wave, mtile, row, col (+1 pad)

    // --- load W slice as B-fragments into registers (bf16), one-time ---
    // B-frag: lane holds B[k = quad*8 + jj][n = lane&15], 8 consecutive k per k-iter.
    short8 bfrag[8];
    {
        const int kb0 = wave * 256;
        const int col = ((nidx >> 2) << 9) + j0 + (nidx & 3);  // 512*gate + j0 + r
        #pragma unroll
        for (int i = 0; i < 8; ++i) {
            short8 v;
            #pragma unroll
            for (int jj = 0; jj < 8; ++jj) {
                int k = kb0 + i * 32 + quad * 8 + jj;
                v[jj] = (short)f2bf(W[k * (4 * Hz) + col]);
            }
            bfrag[i] = v;
        }
    }

    // --- epilogue thread state: bias + cell state in registers ---
    float bia[4][2];
    float creg[2] = {0.f, 0.f};
    if (tid < 64) {
        const int jp = tid & 1;
        #pragma unroll
        for (int s4 = 0; s4 < 4; ++s4)
            #pragma unroll
            for (int jj = 0; jj < 2; ++jj)
                bia[s4][jj] = bias[(s4 << 9) + j0 + jp * 2 + jj];
    }

    int par = 0;
    for (int s = 0; s < Tz; ++s) {
        const int t = dir ? (Tz - 1 - s) : s;
        f32x4 acc0 = {0.f, 0.f, 0.f, 0.f};
        f32x4 acc1 = {0.f, 0.f, 0.f, 0.f};

        if (wave < 2) {
            // x part (K in [0,512)) — independent of h, overlaps the barrier wait.
            const int kb = wave * 256;
            short8 a0[8], a1[8];
            if (XB) {
                #pragma unroll
                for (int i = 0; i < 8; ++i) {
                    int k = kb + i * 32 + quad * 8;
                    a0[i] = *(const short8*)(xbf + ((nidx * Tz + t) * Dz + k));
                    a1[i] = *(const short8*)(xbf + (((nidx + 16) * Tz + t) * Dz + k));
                }
            } else {
                #pragma unroll
                for (int i = 0; i < 8; ++i) {
                    int k = kb + i * 32 + quad * 8;
                    const float* q0 = xf + ((nidx * Tz + t) * Dz + k);
                    const float* q1 = xf + (((nidx + 16) * Tz + t) * Dz + k);
                    short8 s0, s1;
                    #pragma unroll
                    for (int jj = 0; jj < 8; ++jj) {
                        s0[jj] = (short)f2bf(q0[jj]);
                        s1[jj] = (short)f2bf(q1[jj]);
                    }
                    a0[i] = s0; a1[i] = s1;
                }
            }
            #pragma unroll
            for (int i = 0; i < 8; ++i) {
                acc0 = __builtin_amdgcn_mfma_f32_16x16x32_bf16(a0[i], bfrag[i], acc0, 0, 0, 0);
                acc1 = __builtin_amdgcn_mfma_f32_16x16x32_bf16(a1[i], bfrag[i], acc1, 0, 0, 0);
            }
        } else {
            // h part: wait for all WGs of this direction to have published h(s-1).
            const unsigned target = (unsigned)(GPD * s);
            while (__hip_atomic_load(cnt, __ATOMIC_RELAXED, __HIP_MEMORY_SCOPE_AGENT) < target)
                __builtin_amdgcn_s_sleep(2);
            asm volatile("" ::: "memory");
            const unsigned long long* hb = (const unsigned long long*)(hbase + par * 32768);
            const int jb = (wave - 2) * 256;
            short8 a0[8], a1[8];
            #pragma unroll
            for (int i = 0; i < 8; ++i) {
                int j  = jb + i * 32 + quad * 8;
                int i0 = (nidx * Hz + j) >> 2;          // u64 index (4 bf16 each)
                int i1 = ((nidx + 16) * Hz + j) >> 2;
                unsigned long long l00 = __hip_atomic_load(hb + i0,     __ATOMIC_RELAXED, __HIP_MEMORY_SCOPE_AGENT);
                unsigned long long l01 = __hip_atomic_load(hb + i0 + 1, __ATOMIC_RELAXED, __HIP_MEMORY_SCOPE_AGENT);
                unsigned long long l10 = __hip_atomic_load(hb + i1,     __ATOMIC_RELAXED, __HIP_MEMORY_SCOPE_AGENT);
                unsigned long long l11 = __hip_atomic_load(hb + i1 + 1, __ATOMIC_RELAXED, __HIP_MEMORY_SCOPE_AGENT);
                a0[i] = mk8(l00, l01);
                a1[i] = mk8(l10, l11);
            }
            #pragma unroll
            for (int i = 0; i < 8; ++i) {
                acc0 = __builtin_amdgcn_mfma_f32_16x16x32_bf16(a0[i], bfrag[i], acc0, 0, 0, 0);
                acc1 = __builtin_amdgcn_mfma_f32_16x16x32_bf16(a1[i], bfrag[i], acc1, 0, 0, 0);
            }
        }

        // C/D layout: col = lane&15, row = quad*4 + reg
        {
            const int r0 = quad * 4;
            #pragma unroll
            for (int r = 0; r < 4; ++r) {
                part[wave][0][r0 + r][nidx] = acc0[r];
                part[wave][1][r0 + r][nidx] = acc1[r];
            }
        }
        __syncthreads();

        if (tid < 64) {   // 64 threads: b = tid>>1 (32), jp = tid&1 -> 2 j-cols each
            const int b = tid >> 1, jp = tid & 1;
            const int mt = b >> 4, row = b & 15;
            float hv[2];
            #pragma unroll
            for (int jj = 0; jj < 2; ++jj) {
                const int r = jp * 2 + jj;
                float zi = bia[0][jj], zf = bia[1][jj], zo = bia[2][jj], zg = bia[3][jj];
                #pragma unroll
                for (int w = 0; w < 4; ++w) {
                    zi += part[w][mt][row][r];
                    zf += part[w][mt][row][4 + r];
                    zo += part[w][mt][row][8 + r];
                    zg += part[w][mt][row][12 + r];
                }
                float c = fsig(zf) * creg[jj] + fsig(zi) * ftanh(zg);
                creg[jj] = c;
                hv[jj] = fsig(zo) * ftanh(c);
            }
            const int j = j0 + jp * 2;
            float* op = out + (size_t)(b * Tz + t) * (2 * Hz) + dir * Hz + j;
            op[0] = hv[0];
            op[1] = hv[1];
            unsigned hu = (unsigned)f2bf(hv[0]) | ((unsigned)f2bf(hv[1]) << 16);
            unsigned* hw = (unsigned*)(hbase + (par ^ 1) * 32768);
            __hip_atomic_store(hw + b * (Hz / 2) + (j >> 1), hu,
                               __ATOMIC_RELAXED, __HIP_MEMORY_SCOPE_AGENT);
        }

        // Drain stores (agent-scope stores acked at LLC), then publish arrival.
        asm volatile("s_waitcnt vmcnt(0)" ::: "memory");
        __syncthreads();
        if (tid == 0)
            __hip_atomic_fetch_add(cnt, 1u, __ATOMIC_RELAXED, __HIP_MEMORY_SCOPE_AGENT);
        par ^= 1;
    }
}

extern "C" void kernel_launch(void* const* d_in, const int* in_sizes, int n_in,
                              void* d_out, int out_size, void* d_ws, size_t ws_size,
                              hipStream_t stream) {
    const float* x  = (const float*)d_in[0];
    const float* Wf = (const float*)d_in[1];
    const float* bf = (const float*)d_in[2];
    const float* Wb = (const float*)d_in[3];
    const float* bb = (const float*)d_in[4];
    float* out = (float*)d_out;
    unsigned char* ws = (unsigned char*)d_ws;
    const bool xb = (ws_size >= WS_NEED);

    init_kernel<<<8192, 256, 0, stream>>>(x, ws, xb ? 1 : 0);
    if (xb)
        lstm_kernel<true><<<2 * GPD, 256, 0, stream>>>(x, Wf, bf, Wb, bb, out, ws);
    else
        lstm_kernel<false><<<2 * GPD, 256, 0, stream>>>(x, Wf, bf, Wb, bb, out, ws);
}

// Round 2
// 2087.920 us; speedup vs baseline: 1.9282x; 1.9282x over previous
//
#include <hip/hip_runtime.h>
#include <hip/hip_bf16.h>

// Bi-LSTM persistent kernel v2. B=32, T=512, D=H=512.
// 4 sync groups = dir(2) x batch-half(2); each group = 32 WGs, 16 batch rows,
// private barrier counter. Each WG owns 16 h-cols (64 gate cols: ntile==gate).
#define Bz 32
#define Tz 512
#define Dz 512
#define Hz 512
#define NG 4      // sync groups
#define GWG 32    // workgroups per group (arrivals per barrier)
#define ROWS 16   // batch rows per group (one MFMA m-tile)
#define COLS 16   // h-cols per WG

typedef __attribute__((ext_vector_type(8))) short short8;
typedef __attribute__((ext_vector_type(4))) short short4v;
typedef __attribute__((ext_vector_type(4))) float f32x4;

#define HBUF (ROWS * Hz * 2)                 // 16 KB per (group,parity)
#define WS_CNT 0                             // NG counters, 128B apart
#define WS_H   512
#define WS_X   (512 + NG * 2 * HBUF)         // x in bf16: 16 MB
#define WS_NEED ((size_t)WS_X + (size_t)Bz * Tz * Dz * 2)

__device__ __forceinline__ unsigned short f2bf(float f) {
    return __builtin_bit_cast(unsigned short, __float2bfloat16(f));
}
__device__ __forceinline__ float rcp_(float x) { return __builtin_amdgcn_rcpf(x); }
__device__ __forceinline__ float fsig(float x) { return rcp_(1.0f + __expf(-x)); }
__device__ __forceinline__ float ftanh(float x) {
    float t = __expf(-2.0f * fabsf(x));
    return copysignf((1.0f - t) * rcp_(1.0f + t), x);
}
__device__ __forceinline__ short8 mk8(unsigned long long lo, unsigned long long hi) {
    short4v a = __builtin_bit_cast(short4v, lo);
    short4v b = __builtin_bit_cast(short4v, hi);
    short8 r;
    r[0]=a[0]; r[1]=a[1]; r[2]=a[2]; r[3]=a[3];
    r[4]=b[0]; r[5]=b[1]; r[6]=b[2]; r[7]=b[3];
    return r;
}

__global__ void init_kernel(const float* __restrict__ x, unsigned char* __restrict__ ws, int do_x) {
    int tid = blockIdx.x * blockDim.x + threadIdx.x;
    unsigned int* w32 = (unsigned int*)ws;
    if (tid < (WS_X / 4)) w32[tid] = 0u;   // counters + all h buffers
    if (do_x) {
        const int n4 = (Bz * Tz * Dz) / 4;
        if (tid < n4) {
            const float4* xin = (const float4*)x;
            float4 v = xin[tid];
            unsigned int u0 = (unsigned)f2bf(v.x) | ((unsigned)f2bf(v.y) << 16);
            unsigned int u1 = (unsigned)f2bf(v.z) | ((unsigned)f2bf(v.w) << 16);
            unsigned int* xo = (unsigned int*)(ws + WS_X);
            xo[tid * 2]     = u0;
            xo[tid * 2 + 1] = u1;
        }
    }
}

template <bool XB>
__launch_bounds__(256, 1)
__global__ void lstm_kernel(const float* __restrict__ xf,
                            const float* __restrict__ Wf, const float* __restrict__ bf,
                            const float* __restrict__ Wb, const float* __restrict__ bb,
                            float* __restrict__ out, unsigned char* __restrict__ ws) {
    const int bi   = blockIdx.x;
    const int dir  = bi & 1;
    const int grp  = (bi >> 1) & 1;
    const int wg   = bi >> 2;            // 0..31
    const int gid  = dir * 2 + grp;
    const int j0   = wg * COLS;
    const int b0   = grp * ROWS;
    const int tid  = threadIdx.x;
    const int wave = tid >> 6;
    const int lane = tid & 63;
    const int nidx = lane & 15;          // B-frag col n / A-frag row m
    const int quad = lane >> 4;

    const float* W    = dir ? Wb : Wf;
    const float* bias = dir ? bb : bf;

    unsigned int* cnt = (unsigned int*)(ws + WS_CNT + gid * 128);
    unsigned char* hbase = ws + WS_H + gid * 2 * HBUF;   // + parity*HBUF
    const unsigned short* xbf = (const unsigned short*)(ws + WS_X);

    __shared__ float part[4][4][16][17];  // wave, gate, row, col (+1 pad)

    // --- one-time: W slice as B-fragments in registers (bf16) ---
    // wave 0/1: K rows [0,256)/[256,512) of Wx; wave 2/3: rows [0,256)/[256,512) of Wh.
    short8 bfrag[8][4];
    {
        const int krow0 = (wave < 2) ? wave * 256 : 512 + (wave - 2) * 256;
        #pragma unroll
        for (int i = 0; i < 8; ++i) {
            #pragma unroll
            for (int g = 0; g < 4; ++g) {
                short8 v;
                #pragma unroll
                for (int jj = 0; jj < 8; ++jj) {
                    int krow = krow0 + i * 32 + quad * 8 + jj;
                    v[jj] = (short)f2bf(W[krow * (4 * Hz) + g * 512 + j0 + nidx]);
                }
                bfrag[i][g] = v;
            }
        }
    }

    // --- per-thread epilogue state: one (row,col) each ---
    const int erow = tid >> 4;           // batch row within group
    const int ecol = tid & 15;           // h-col within WG
    float bia[4];
    #pragma unroll
    for (int g = 0; g < 4; ++g) bia[g] = bias[g * 512 + j0 + ecol];
    float creg = 0.f;
    const size_t outbase = ((size_t)(b0 + erow) * Tz) * (2 * Hz) + dir * Hz + j0 + ecol;

    int par = 0;
    for (int s = 0; s < Tz; ++s) {
        const int t = dir ? (Tz - 1 - s) : s;
        f32x4 acc[4] = {{0,0,0,0},{0,0,0,0},{0,0,0,0},{0,0,0,0}};

        if (wave < 2) {
            // x part — independent of h, overlaps the barrier wait on waves 2-3.
            const int kb = wave * 256;
            short8 a[8];
            if (XB) {
                #pragma unroll
                for (int i = 0; i < 8; ++i) {
                    int k = kb + i * 32 + quad * 8;
                    a[i] = *(const short8*)(xbf + (((b0 + nidx) * Tz + t) * Dz + k));
                }
            } else {
                #pragma unroll
                for (int i = 0; i < 8; ++i) {
                    int k = kb + i * 32 + quad * 8;
                    const float* q = xf + (((b0 + nidx) * Tz + t) * Dz + k);
                    short8 sv;
                    #pragma unroll
                    for (int jj = 0; jj < 8; ++jj) sv[jj] = (short)f2bf(q[jj]);
                    a[i] = sv;
                }
            }
            #pragma unroll
            for (int i = 0; i < 8; ++i)
                #pragma unroll
                for (int g = 0; g < 4; ++g)
                    acc[g] = __builtin_amdgcn_mfma_f32_16x16x32_bf16(a[i], bfrag[i][g], acc[g], 0, 0, 0);
        } else {
            // h part: wait for all WGs of this group to publish h(s-1).
            const unsigned target = (unsigned)(GWG * s);
            while (__hip_atomic_load(cnt, __ATOMIC_RELAXED, __HIP_MEMORY_SCOPE_AGENT) < target)
                __builtin_amdgcn_s_sleep(1);
            asm volatile("" ::: "memory");
            const unsigned long long* hb = (const unsigned long long*)(hbase + par * HBUF);
            const int kb = (wave - 2) * 256;
            short8 a[8];
            #pragma unroll
            for (int i = 0; i < 8; ++i) {
                int k  = kb + i * 32 + quad * 8;
                int i0 = (nidx * Hz + k) >> 2;   // u64 index (4 bf16 each)
                unsigned long long l0 = __hip_atomic_load(hb + i0,     __ATOMIC_RELAXED, __HIP_MEMORY_SCOPE_AGENT);
                unsigned long long l1 = __hip_atomic_load(hb + i0 + 1, __ATOMIC_RELAXED, __HIP_MEMORY_SCOPE_AGENT);
                a[i] = mk8(l0, l1);
            }
            #pragma unroll
            for (int i = 0; i < 8; ++i)
                #pragma unroll
                for (int g = 0; g < 4; ++g)
                    acc[g] = __builtin_amdgcn_mfma_f32_16x16x32_bf16(a[i], bfrag[i][g], acc[g], 0, 0, 0);
        }

        // C/D layout: col = lane&15, row = quad*4 + reg
        {
            const int r0 = quad * 4;
            #pragma unroll
            for (int g = 0; g < 4; ++g)
                #pragma unroll
                for (int r = 0; r < 4; ++r)
                    part[wave][g][r0 + r][nidx] = acc[g][r];
        }
        __syncthreads();

        // epilogue: one (row,col) per thread
        float hv;
        {
            float z[4];
            #pragma unroll
            for (int g = 0; g < 4; ++g)
                z[g] = bia[g] + part[0][g][erow][ecol] + part[1][g][erow][ecol]
                             + part[2][g][erow][ecol] + part[3][g][erow][ecol];
            float c = fsig(z[1]) * creg + fsig(z[0]) * ftanh(z[3]);
            creg = c;
            hv = fsig(z[2]) * ftanh(c);
            unsigned short* hw = (unsigned short*)(hbase + (par ^ 1) * HBUF);
            __hip_atomic_store(hw + erow * Hz + j0 + ecol, f2bf(hv),
                               __ATOMIC_RELAXED, __HIP_MEMORY_SCOPE_AGENT);
        }

        // Drain h stores (acked at LLC), then publish arrival; out-store after.
        asm volatile("s_waitcnt vmcnt(0)" ::: "memory");
        __syncthreads();
        if (tid == 0)
            __hip_atomic_fetch_add(cnt, 1u, __ATOMIC_RELAXED, __HIP_MEMORY_SCOPE_AGENT);
        out[outbase + (size_t)t * (2 * Hz)] = hv;
        par ^= 1;
    }
}

extern "C" void kernel_launch(void* const* d_in, const int* in_sizes, int n_in,
                              void* d_out, int out_size, void* d_ws, size_t ws_size,
                              hipStream_t stream) {
    const float* x  = (const float*)d_in[0];
    const float* Wf = (const float*)d_in[1];
    const float* bf = (const float*)d_in[2];
    const float* Wb = (const float*)d_in[3];
    const float* bb = (const float*)d_in[4];
    float* out = (float*)d_out;
    unsigned char* ws = (unsigned char*)d_ws;
    const bool xb = (ws_size >= WS_NEED);

    init_kernel<<<8192, 256, 0, stream>>>(x, ws, xb ? 1 : 0);
    if (xb)
        lstm_kernel<true><<<NG * GWG, 256, 0, stream>>>(x, Wf, bf, Wb, bb, out, ws);
    else
        lstm_kernel<false><<<NG * GWG, 256, 0, stream>>>(x, Wf, bf, Wb, bb, out, ws);
}